// Round 5
// baseline (717.697 us; speedup 1.0000x reference)
//
#include <hip/hip_runtime.h>
#include <math.h>

// Problem constants (from reference)
constexpr int B    = 512;
constexpr int NPG  = 200;    // nodes per graph, stage 0
constexpr int EPER = 2000;   // edges per graph
constexpr int EMB  = 9;
constexpr int HID  = 128;
constexpr int K1   = 160;    // ceil(0.8*200)
constexpr int K2   = 128;    // ceil(0.8*160)
constexpr int K3   = 103;    // ceil(0.8*128)
constexpr int N0   = B * NPG;   // 102400
constexpr int N1   = B * K1;    // 81920
constexpr int N2   = B * K2;    // 65536
constexpr int N3   = B * K3;    // 52736
constexpr int E    = B * EPER;  // 1024000

// ---------------------------------------------------------------------------
// Embedding gather: x0[n][:] = emb[node_ids[n]][:]
__global__ __launch_bounds__(256) void k_gather(const int* __restrict__ node_ids,
                         const float* __restrict__ emb,
                         float* __restrict__ x0) {
    int n = blockIdx.x * blockDim.x + threadIdx.x;
    if (n < N0) {
        int id = node_ids[n];
        #pragma unroll
        for (int j = 0; j < EMB; j++) x0[n * EMB + j] = emb[id * EMB + j];
    }
}

// ---------------------------------------------------------------------------
// Stage-1 aggregation (width EMB=9), all edges valid. One block per graph,
// accumulate in LDS, write the MEAN directly (conv1 needs no cnt).
__global__ __launch_bounds__(256) void k_agg9(const float* __restrict__ x0,
                       const int* __restrict__ esrc,
                       const int* __restrict__ edst,
                       float* __restrict__ m9) {
    int g = blockIdx.x;
    __shared__ float lacc[NPG * EMB];
    __shared__ float lcnt[NPG];
    for (int i = threadIdx.x; i < NPG * EMB; i += 256) lacc[i] = 0.f;
    for (int i = threadIdx.x; i < NPG; i += 256) lcnt[i] = 0.f;
    __syncthreads();
    const int ebase = g * EPER;
    const int nbase = g * NPG;
    for (int idx = threadIdx.x; idx < EPER * EMB; idx += 256) {
        int el = idx / EMB;
        int j  = idx - el * EMB;
        int e  = ebase + el;
        int src = esrc[e];
        int dl  = edst[e] - nbase;
        atomicAdd(&lacc[dl * EMB + j], x0[src * EMB + j]);
        if (j == 0) atomicAdd(&lcnt[dl], 1.f);
    }
    __syncthreads();
    for (int i = threadIdx.x; i < NPG * EMB; i += 256) {
        int row = i / EMB;
        m9[nbase * EMB + i] = lacc[i] / fmaxf(lcnt[row], 1.f);
    }
}

// ---------------------------------------------------------------------------
// Stage-2/3 aggregation, CSR-based, with FUSED edge remap: takes the raw
// edge list + mapping chain (map1[, map2]) and computes validity inline.
// One block per (graph, feature-half). Emits the MEAN directly.
__global__ __launch_bounds__(256) void k_aggcsr(const float* __restrict__ x,
                         const int* __restrict__ es,
                         const int* __restrict__ ed,
                         const int* __restrict__ map1,
                         const int* __restrict__ map2,   // may be null
                         int npc,
                         float* __restrict__ sout) {
    int g = blockIdx.x;
    int w = blockIdx.y;   // feature half (0/1)
    int tid = threadIdx.x;  // 256
    __shared__ int deg[256];
    __shared__ int scanbuf[256];
    __shared__ int off[257];
    __shared__ int cur[256];
    __shared__ int csr[EPER];

    deg[tid] = 0;
    __syncthreads();
    const int ebase = g * EPER;
    const int nbase = g * npc;
    // pass 1: degrees (remap on the fly)
    for (int e = tid; e < EPER; e += 256) {
        int a = map1[es[ebase + e]];
        int b = map1[ed[ebase + e]];
        if (map2) {
            a = (a >= 0) ? map2[a] : -1;
            b = (b >= 0) ? map2[b] : -1;
        }
        if (a >= 0 && b >= 0) atomicAdd(&deg[b - nbase], 1);
    }
    __syncthreads();
    // Hillis-Steele inclusive scan over 256 entries
    int v = deg[tid];
    scanbuf[tid] = v;
    __syncthreads();
    #pragma unroll
    for (int d = 1; d < 256; d <<= 1) {
        int t = (tid >= d) ? scanbuf[tid - d] : 0;
        __syncthreads();
        scanbuf[tid] += t;
        __syncthreads();
    }
    if (tid == 0) off[0] = 0;
    off[tid + 1] = scanbuf[tid];
    __syncthreads();
    cur[tid] = off[tid];
    __syncthreads();
    // pass 2: scatter src ids into CSR slots
    for (int e = tid; e < EPER; e += 256) {
        int a = map1[es[ebase + e]];
        int b = map1[ed[ebase + e]];
        if (map2) {
            a = (a >= 0) ? map2[a] : -1;
            b = (b >= 0) ? map2[b] : -1;
        }
        if (a >= 0 && b >= 0) {
            int slot = atomicAdd(&cur[b - nbase], 1);
            csr[slot] = a;
        }
    }
    __syncthreads();
    // phase 2: one wave per dst, register accumulation, write mean
    int lane = tid & 63, wv = tid >> 6;
    int hoff = w * 64 + lane;
    for (int dl = wv; dl < npc; dl += 4) {
        int beg = off[dl], end = off[dl + 1];
        float acc = 0.f, acc2 = 0.f;
        int t = beg;
        for (; t + 1 < end; t += 2) {
            acc  += x[(long)csr[t]     * HID + hoff];
            acc2 += x[(long)csr[t + 1] * HID + hoff];
        }
        if (t < end) acc += x[(long)csr[t] * HID + hoff];
        float inv = 1.f / (float)((end - beg) > 1 ? (end - beg) : 1);
        sout[(long)(nbase + dl) * HID + hoff] = (acc + acc2) * inv;
    }
}

// ---------------------------------------------------------------------------
// Conv1: out[n][h] = relu( m9[n] . w1n[h] + x0[n] . w1r[h] + b[h] )
// m9 already holds the neighbor mean.
template <int NB>
__global__ __launch_bounds__(128) void k_conv1(const float* __restrict__ m9,
                        const float* __restrict__ x0,
                        const float* __restrict__ wn,
                        const float* __restrict__ wr,
                        const float* __restrict__ bb,
                        float* __restrict__ out) {
    __shared__ float sm[NB][EMB];
    __shared__ float sx[NB][EMB];
    int nb0 = blockIdx.x * NB;
    int h = threadIdx.x;  // 128
    for (int i = h; i < NB * EMB; i += 128) {
        int sl = i / EMB, j = i - sl * EMB;
        int n = nb0 + sl;
        sm[sl][j] = m9[n * EMB + j];
        sx[sl][j] = x0[n * EMB + j];
    }
    __syncthreads();
    float acc[NB];
    #pragma unroll
    for (int sl = 0; sl < NB; sl++) acc[sl] = bb[h];
    #pragma unroll
    for (int j = 0; j < EMB; j++) {
        float a = wn[h * EMB + j];
        float r = wr[h * EMB + j];
        #pragma unroll
        for (int sl = 0; sl < NB; sl++) acc[sl] += sm[sl][j] * a + sx[sl][j] * r;
    }
    #pragma unroll
    for (int sl = 0; sl < NB; sl++)
        out[(long)(nb0 + sl) * HID + h] = fmaxf(acc[sl], 0.f);
}

// ---------------------------------------------------------------------------
// Conv2/3 as LDS-tiled fp32 GEMM, K=256 (concat [mean_s, x] vs [wn; wr]).
// Row-major LDS tiles, pitch 36 floats, 16B-chunk XOR swizzle
// (chunk' = kq ^ (row>>3)): staging is direct float4 -> ds_write_b128
// (conflict-free), A-reads hit 4 distinct bank-quads (conflict-free),
// B-reads are 2-way (free). Compute in k-quads: per kq, 8 A-frags (float4)
// + per-col B-frag, 256 FMAs per 16 ds_read_b128.
// In-place safe (out may alias s): block reads only its own 128 rows of s
// (all during prefetch of chunks 0..3), stores only in the epilogue.
constexpr int TP = 36;  // LDS row pitch in floats (9 bank-quads)
__global__ __launch_bounds__(256, 3) void k_convgemm(
        const float* s,                      // neighbor MEAN; may alias out
        const float* xin,
        const float* __restrict__ wn,
        const float* __restrict__ wr,
        const float* __restrict__ bb,
        float* out) {
    __shared__ float As[128 * TP];
    __shared__ float Bs[128 * TP];
    const int tid = threadIdx.x;
    const long row0 = (long)blockIdx.x * 128;
    const int srow = tid >> 3;      // 0..31 (+32i)
    const int skq  = tid & 7;       // staging k-quad
    const int tc = tid & 15, tr = tid >> 4;

    float acc[8][8];
    #pragma unroll
    for (int r = 0; r < 8; r++)
        #pragma unroll
        for (int c = 0; c < 8; c++) acc[r][c] = 0.f;

    // prefetch chunk 0
    float4 av[4], bv[4];
    #pragma unroll
    for (int i = 0; i < 4; i++) {
        int m = srow + 32 * i;
        av[i] = *(const float4*)(s  + (row0 + m) * HID + skq * 4);
        bv[i] = *(const float4*)(wn + (size_t)m * HID + skq * 4);
    }

    for (int ch = 0; ch < 8; ch++) {
        __syncthreads();
        #pragma unroll
        for (int i = 0; i < 4; i++) {
            int m = srow + 32 * i;
            int swz = skq ^ ((m >> 3) & 7);
            *(float4*)&As[m * TP + swz * 4] = av[i];
            *(float4*)&Bs[m * TP + swz * 4] = bv[i];
        }
        __syncthreads();
        if (ch + 1 < 8) {
            const float* xs = (ch + 1 < 4) ? s : xin;
            const float* ws = (ch + 1 < 4) ? wn : wr;
            int k0 = ((ch + 1) & 3) * 32;
            #pragma unroll
            for (int i = 0; i < 4; i++) {
                int m = srow + 32 * i;
                av[i] = *(const float4*)(xs + (row0 + m) * HID + k0 + skq * 4);
                bv[i] = *(const float4*)(ws + (size_t)m * HID + k0 + skq * 4);
            }
        }
        for (int kq = 0; kq < 8; kq++) {
            float4 af[8];
            #pragma unroll
            for (int rr = 0; rr < 8; rr++) {
                int m = tr * 8 + rr;
                af[rr] = *(const float4*)&As[m * TP + (kq ^ (tr & 7)) * 4];
            }
            #pragma unroll
            for (int cp = 0; cp < 8; cp++) {
                int col = (cp < 4) ? (tc * 4 + cp) : (64 + tc * 4 + (cp - 4));
                float4 bf = *(const float4*)&Bs[col * TP + (kq ^ ((col >> 3) & 7)) * 4];
                #pragma unroll
                for (int rr = 0; rr < 8; rr++)
                    acc[rr][cp] += af[rr].x * bf.x + af[rr].y * bf.y +
                                   af[rr].z * bf.z + af[rr].w * bf.w;
            }
        }
    }

    // epilogue: bias + relu, coalesced float4 stores
    float4 bias0 = *(const float4*)&bb[tc * 4];
    float4 bias1 = *(const float4*)&bb[64 + tc * 4];
    #pragma unroll
    for (int r = 0; r < 8; r++) {
        long m = row0 + tr * 8 + r;
        float4 o0, o1;
        o0.x = fmaxf(acc[r][0] + bias0.x, 0.f);
        o0.y = fmaxf(acc[r][1] + bias0.y, 0.f);
        o0.z = fmaxf(acc[r][2] + bias0.z, 0.f);
        o0.w = fmaxf(acc[r][3] + bias0.w, 0.f);
        o1.x = fmaxf(acc[r][4] + bias1.x, 0.f);
        o1.y = fmaxf(acc[r][5] + bias1.y, 0.f);
        o1.z = fmaxf(acc[r][6] + bias1.z, 0.f);
        o1.w = fmaxf(acc[r][7] + bias1.w, 0.f);
        *(float4*)(out + m * HID + tc * 4) = o0;
        *(float4*)(out + m * HID + 64 + tc * 4) = o1;
    }
}

// ---------------------------------------------------------------------------
// TopK pool + FUSED global max/mean pool.
// score = tanh(x.p/||p||); jax.lax.top_k semantics (descending, lower index
// wins ties); xout[g*k+rank] = x[node]*score; mapping old->new (or -1);
// gout[g][0:128] = max over kept rows, gout[g][128:256] = mean.
__global__ __launch_bounds__(256) void k_pool(const float* __restrict__ x,
                       const float* __restrict__ p,
                       int npc, int k,
                       float* __restrict__ xout,
                       int* __restrict__ mapping,
                       float* __restrict__ gout) {
    int g = blockIdx.x;
    int tid = threadIdx.x;  // 256
    __shared__ float sc[256];
    __shared__ int   pos[256];
    __shared__ float redm[128];
    __shared__ float reds[128];
    int lane = tid & 63, wv = tid >> 6;
    float pl0 = p[lane], pl1 = p[64 + lane];
    // ||p||^2 via butterfly
    float pp = pl0 * pl0 + pl1 * pl1;
    #pragma unroll
    for (int o = 32; o >= 1; o >>= 1) pp += __shfl_xor(pp, o, 64);
    float nrm = sqrtf(pp);
    // scores: one wave per row, coalesced reads + butterfly reduce
    for (int i = wv; i < npc; i += 4) {
        const float* xr = x + (long)(g * npc + i) * HID;
        float d = xr[lane] * pl0 + xr[64 + lane] * pl1;
        #pragma unroll
        for (int o = 32; o >= 1; o >>= 1) d += __shfl_xor(d, o, 64);
        if (lane == 0) sc[i] = tanhf(d / nrm);
    }
    __syncthreads();
    // rank = position in descending stable order
    if (tid < npc) {
        float scv = sc[tid];
        int rank = 0;
        for (int j = 0; j < npc; j++) {
            float o = sc[j];
            rank += (o > scv) || (o == scv && j < tid);
        }
        bool keep = rank < k;
        pos[tid] = keep ? rank : -1;
        mapping[g * npc + tid] = keep ? (g * k + rank) : -1;
    }
    __syncthreads();
    // gather + scale into new ordering; accumulate global max/sum per column
    int h = tid & 127, half = tid >> 7;
    float pmax = -INFINITY, psum = 0.f;
    for (int i = half; i < npc; i += 2) {
        int r = pos[i];
        if (r >= 0) {
            float v = x[(long)(g * npc + i) * HID + h] * sc[i];
            xout[(long)(g * k + r) * HID + h] = v;
            pmax = fmaxf(pmax, v);
            psum += v;
        }
    }
    if (half) { redm[h] = pmax; reds[h] = psum; }
    __syncthreads();
    if (!half) {
        pmax = fmaxf(pmax, redm[h]);
        psum += reds[h];
        gout[g * 256 + h] = pmax;
        gout[g * 256 + 128 + h] = psum / (float)k;
    }
}

// ---------------------------------------------------------------------------
// MLP head: h=g1+g2+g3; relu(h@lw1.T+lb1); relu(@lw2.T+lb2); sigmoid(@lw3.T+lb3)
__global__ __launch_bounds__(128) void k_mlp(const float* __restrict__ g1, const float* __restrict__ g2,
                      const float* __restrict__ g3,
                      const float* __restrict__ lw1, const float* __restrict__ lb1,
                      const float* __restrict__ lw2, const float* __restrict__ lb2,
                      const float* __restrict__ lw3, const float* __restrict__ lb3,
                      float* __restrict__ out) {
    int g = blockIdx.x, t = threadIdx.x;  // 128 threads
    __shared__ float h0[256];
    __shared__ float h1[128];
    __shared__ float h2r[64];
    h0[t]       = g1[g * 256 + t] + g2[g * 256 + t] + g3[g * 256 + t];
    h0[t + 128] = g1[g * 256 + 128 + t] + g2[g * 256 + 128 + t] + g3[g * 256 + 128 + t];
    __syncthreads();
    float a = lb1[t];
    #pragma unroll 4
    for (int j = 0; j < 256; j++) a += h0[j] * lw1[t * 256 + j];
    h1[t] = fmaxf(a, 0.f);
    __syncthreads();
    if (t < 64) {
        float a2 = lb2[t];
        #pragma unroll 4
        for (int j = 0; j < 128; j++) a2 += h1[j] * lw2[t * 128 + j];
        h2r[t] = fmaxf(a2, 0.f) * lw3[t];
    }
    __syncthreads();
    if (t == 0) {
        float s = 0.f;
        for (int j = 0; j < 64; j++) s += h2r[j];
        s += lb3[0];
        out[g] = 1.f / (1.f + expf(-s));
    }
}

// ---------------------------------------------------------------------------
extern "C" void kernel_launch(void* const* d_in, const int* in_sizes, int n_in,
                              void* d_out, int out_size, void* d_ws, size_t ws_size,
                              hipStream_t stream) {
    const int*   node_ids = (const int*)d_in[0];
    const int*   ei   = (const int*)d_in[1];   // edge_index (2, E)
    const float* emb  = (const float*)d_in[3];
    const float* w1n  = (const float*)d_in[4];
    const float* w1r  = (const float*)d_in[5];
    const float* b1   = (const float*)d_in[6];
    const float* w2n  = (const float*)d_in[7];
    const float* w2r  = (const float*)d_in[8];
    const float* b2   = (const float*)d_in[9];
    const float* w3n  = (const float*)d_in[10];
    const float* w3r  = (const float*)d_in[11];
    const float* b3   = (const float*)d_in[12];
    const float* p1   = (const float*)d_in[13];
    const float* p2   = (const float*)d_in[14];
    const float* p3   = (const float*)d_in[15];
    const float* lw1  = (const float*)d_in[16];
    const float* lb1  = (const float*)d_in[17];
    const float* lw2  = (const float*)d_in[18];
    const float* lb2  = (const float*)d_in[19];
    const float* lw3  = (const float*)d_in[20];
    const float* lb3  = (const float*)d_in[21];
    float* out = (float*)d_out;

    // Workspace layout (floats). x0/m9 alias the front of D (dead before
    // D's first real use as pool-1 output).
    float* ws  = (float*)d_ws;
    float* C   = ws;                           // N0*HID   (x1 / mean / x2 / x3)
    float* D   = C + (size_t)N0 * HID;         // N1*HID   (x1p / x2p / x3p)
    float* x0  = D;                            // N0*EMB   (stage 1 only)
    float* m9  = D + (size_t)N0 * EMB;         // N0*EMB   (stage 1 only)
    float* g1  = D + (size_t)N1 * HID;         // B*256
    float* g2  = g1 + B * 2 * HID;             // B*256
    float* g3  = g2 + B * 2 * HID;             // B*256
    int* map1  = (int*)(g3 + B * 2 * HID);     // N0
    int* map2  = map1 + N0;                    // N1

    // ---- Stage 1 (EMB -> HID) ----
    k_gather<<<(N0 + 255) / 256, 256, 0, stream>>>(node_ids, emb, x0);
    k_agg9<<<B, 256, 0, stream>>>(x0, ei, ei + E, m9);
    k_conv1<8><<<N0 / 8, 128, 0, stream>>>(m9, x0, w1n, w1r, b1, C);
    k_pool<<<B, 256, 0, stream>>>(C, p1, NPG, K1, D, map1, g1);

    // ---- Stage 2 (HID -> HID), nodes N1 ----
    k_aggcsr<<<dim3(B, 2), 256, 0, stream>>>(D, ei, ei + E, map1, nullptr, K1, C);
    k_convgemm<<<N1 / 128, 256, 0, stream>>>(C, D, w2n, w2r, b2, C);
    k_pool<<<B, 256, 0, stream>>>(C, p2, K1, K2, D, map2, g2);

    // ---- Stage 3 (HID -> HID), nodes N2 ----
    k_aggcsr<<<dim3(B, 2), 256, 0, stream>>>(D, ei, ei + E, map1, map2, K2, C);
    k_convgemm<<<N2 / 128, 256, 0, stream>>>(C, D, w3n, w3r, b3, C);
    k_pool<<<B, 256, 0, stream>>>(C, p3, K2, K3, D, map1 /*scratch*/, g3);

    // ---- Head ----
    k_mlp<<<B, 128, 0, stream>>>(g1, g2, g3, lw1, lb1, lw2, lb2, lw3, lb3, out);
}